// Round 7
// baseline (411.020 us; speedup 1.0000x reference)
//
#include <hip/hip_runtime.h>
#include <hip/hip_bf16.h>
#include <math.h>

#define EPSV 1e-6f

typedef __attribute__((ext_vector_type(8))) short bf16x8;
typedef __attribute__((ext_vector_type(4))) float f32x4;
typedef __attribute__((ext_vector_type(4))) unsigned short u16x4;
typedef __attribute__((ext_vector_type(2))) unsigned int u32x2;

__device__ inline float bf2f(unsigned short u) {
  union { unsigned int i; float f; } v;
  v.i = ((unsigned int)u) << 16;
  return v.f;
}
// RNE bf16 round, no NaN path (all values finite here)
__device__ inline unsigned short f2bf(float f) {
  unsigned int u = __builtin_bit_cast(unsigned int, f);
  u += 0x7FFFu + ((u >> 16) & 1u);
  return (unsigned short)(u >> 16);
}
// HW packed f32x2 -> bf16x2 (RNE), 1 VALU op for 2 values
__device__ inline unsigned int pk2(float lo, float hi) {
  unsigned int r;
  asm("v_cvt_pk_bf16_f32 %0, %1, %2" : "=v"(r) : "v"(lo), "v"(hi));
  return r;
}
// tanh-GELU via exp + hw rcp (no div sequence)
__device__ inline float fast_gelu(float v) {
  float u = 1.5957691216057308f * (v + 0.044715f * v * v * v);
  float t = __expf(-u);
  return v * __builtin_amdgcn_rcpf(1.f + t);
}

// ---- Kernel 0: pack all weights into MFMA B-fragment layout (bf16) ----
// B-frag: [ntile][kstep][lane][8], n=ntile*16+(lane&15), k=kstep*32+(lane>>4)*8+j
__global__ __launch_bounds__(256) void k0_pack(
    const float* __restrict__ qw, const float* __restrict__ aw,
    const float* __restrict__ w1, const float* __restrict__ w2,
    const float* __restrict__ pw, unsigned short* __restrict__ qwp,
    unsigned short* __restrict__ awp, unsigned short* __restrict__ w1p,
    unsigned short* __restrict__ w2p, unsigned short* __restrict__ pwp) {
  int idx = blockIdx.x * 256 + threadIdx.x;
  int lane = idx & 63;
  int l15 = lane & 15, quad = lane >> 4;
  if (idx < 6912) {
    int fi = idx >> 6;
    int ntile = fi / 3, kstep = fi - ntile * 3;
    int n = ntile * 16 + l15, k0 = kstep * 32 + quad * 8;
#pragma unroll
    for (int j = 0; j < 8; ++j)
      qwp[(size_t)idx * 8 + j] = f2bf(qw[(size_t)(k0 + j) * 576 + n]);
  } else if (idx < 11520) {
    int i2 = idx - 6912;
    int fi = i2 >> 6;
    int ntile = fi / 6, kstep = fi - ntile * 6;
    int n = ntile * 16 + l15, k0 = kstep * 32 + quad * 8;
#pragma unroll
    for (int j = 0; j < 8; ++j)
      awp[(size_t)i2 * 8 + j] = f2bf(aw[(size_t)(k0 + j) * 192 + n]);
  } else if (idx < 29952) {
    int i3 = idx - 11520;
    int fi = i3 >> 6;
    int ntile = fi / 6, kstep = fi - ntile * 6;
    int n = ntile * 16 + l15, k0 = kstep * 32 + quad * 8;
#pragma unroll
    for (int j = 0; j < 8; ++j)
      w1p[(size_t)i3 * 8 + j] = f2bf(w1[(size_t)(k0 + j) * 768 + n]);
  } else if (idx < 48384) {
    int i4 = idx - 29952;
    int fi = i4 >> 6;
    int ntile = fi / 24, kstep = fi - ntile * 24;
    int n = ntile * 16 + l15, k0 = kstep * 32 + quad * 8;
#pragma unroll
    for (int j = 0; j < 8; ++j)
      w2p[(size_t)i4 * 8 + j] = f2bf(w2[(size_t)(k0 + j) * 192 + n]);
  } else if (idx < 50688) {
    int i5 = idx - 48384;
    int fi = i5 >> 6;
    int ntile = fi / 3, kstep = fi - ntile * 3;
    int n = ntile * 16 + l15, k0 = kstep * 32 + quad * 8;
#pragma unroll
    for (int j = 0; j < 8; ++j)
      pwp[(size_t)i5 * 8 + j] = f2bf(pw[(size_t)(k0 + j) * 192 + n]);
  }
}

// -- Kernel 1234: whole block fused.
// LDS (40,192 B; x4 = 160,768... no: 40,192*4 = 160,768 > 163,840? yes <= ok):
//   buf1 @0      (27,648): xn -> K[64][200] -> V^T[192][72] -> obb[16][200]
//                          (+yn @6400, hls[16][392] @12800 after V dead)
//   scwb @27,648 (12,544): wbuf[3][16][72] (Q->P, dead after PV)
//                          then sc[16][196] f32 (shortcut -> y; stride 196
//                          breaks the 768B=same-bank 4-way conflict)
// proj merged into Phase A (9 balanced jobs/wave); pooled shortcut rides in
// 24 regs until the B2 write window (base VGPR 60 -> peak ~110 < 128).
__global__ __launch_bounds__(256, 4) void k1234_fused(
    const float* __restrict__ x, const float* __restrict__ n1g,
    const float* __restrict__ n1b, const unsigned short* __restrict__ pwp,
    const float* __restrict__ pb, const unsigned short* __restrict__ qwp,
    const float* __restrict__ qb, const unsigned short* __restrict__ awp,
    const float* __restrict__ ab, const float* __restrict__ n2g,
    const float* __restrict__ n2b, const unsigned short* __restrict__ w1p,
    const float* __restrict__ b1, const unsigned short* __restrict__ w2p,
    const float* __restrict__ b2, float* __restrict__ out) {
  __shared__ __align__(16) unsigned char smem[40192];
  unsigned short (*kk)[200] = (unsigned short (*)[200])smem;   // xn/K/obb
  unsigned short (*vT)[72] = (unsigned short (*)[72])smem;     // V^T (after B1.5)
  unsigned short (*yn)[200] = (unsigned short (*)[200])(smem + 6400);
  unsigned short (*hls)[392] = (unsigned short (*)[392])(smem + 12800);
  unsigned short (*wbuf)[16][72] =
      (unsigned short (*)[16][72])(smem + 27648);
  float (*sc)[196] = (float (*)[196])(smem + 27648);  // aliases wbuf (later)

  int tid = threadIdx.x, wave = tid >> 6, lane = tid & 63;
  int wi = blockIdx.x;
  int b = wi >> 10, nh = (wi >> 5) & 31, nw = wi & 31;
  int grow0 = nh * 8, gcol0 = nw * 8;
  int l15 = lane & 15, quad = lane >> 4;

  // ---- LN1: token tt (0..63) handled by 4 threads (sub 0..3) ----
  {
    int tt = tid >> 2, sub = tid & 3;
    int rr = tt >> 3, cc = tt & 7;
    size_t tok = (size_t)((b * 256 + grow0 + rr) * 256 + gcol0 + cc);
    const f32x4* xr4 = (const f32x4*)(x + tok * 96 + sub * 24);
    f32x4 v[6];
#pragma unroll
    for (int i = 0; i < 6; ++i) v[i] = xr4[i];
    float s = 0.f;
#pragma unroll
    for (int i = 0; i < 6; ++i)
#pragma unroll
      for (int j = 0; j < 4; ++j) s += v[i][j];
    s += __shfl_xor(s, 1);
    s += __shfl_xor(s, 2);
    float mean = s * (1.f / 96.f);
    float q = 0.f;
#pragma unroll
    for (int i = 0; i < 6; ++i)
#pragma unroll
      for (int j = 0; j < 4; ++j) {
        float d = v[i][j] - mean;
        q += d * d;
      }
    q += __shfl_xor(q, 1);
    q += __shfl_xor(q, 2);
    float rstd = rsqrtf(q * (1.f / 96.f) + EPSV);
    const f32x4* g4 = (const f32x4*)(n1g + sub * 24);
    const f32x4* b4 = (const f32x4*)(n1b + sub * 24);
#pragma unroll
    for (int i = 0; i < 6; ++i) {
      f32x4 gg = g4[i], bb = b4[i];
      u32x2 w;
      w[0] = pk2((v[i][0] - mean) * rstd * gg[0] + bb[0],
                 (v[i][1] - mean) * rstd * gg[1] + bb[1]);
      w[1] = pk2((v[i][2] - mean) * rstd * gg[2] + bb[2],
                 (v[i][3] - mean) * rstd * gg[3] + bb[3]);
      *(u32x2*)(&kk[tt][sub * 24 + i * 4]) = w;  // xn aliased into kk
    }
  }
  __syncthreads();  // S1: xn visible

  // A-frags (xw 64x96) from LDS; m = token index (row-major in window)
  bf16x8 areg[4][3];
#pragma unroll
  for (int mt = 0; mt < 4; ++mt)
#pragma unroll
    for (int ks = 0; ks < 3; ++ks)
      areg[mt][ks] = *(const bf16x8*)(&kk[mt * 16 + l15][ks * 32 + quad * 8]);
  __syncthreads();  // S2: xn dead -> kk writable (K)

  // ---- Phase A: Q + K + proj, 9 balanced jobs/wave ----
  // w<3: 4 Q (own head) + 2 K + 3 proj; w3: 6 K + 3 proj.
  // Proj pooled results ride in scr regs until the B2 write window.
  float scr[3][4][2];
#pragma unroll
  for (int aj = 0; aj < 9; ++aj) {
    int type, hh, nt;  // type: 0=Q, 1=K, 2=proj
    if (aj >= 6) {
      type = 2; hh = 0; nt = aj - 6;  // nt = proj nl 0..2
    } else if (wave < 3) {
      if (aj < 4) { type = 0; hh = wave; nt = aj; }
      else { int kidx = wave * 2 + (aj - 4); type = 1; hh = kidx >> 2; nt = kidx & 3; }
    } else {
      int kidx = 6 + aj; type = 1; hh = kidx >> 2; nt = kidx & 3;
    }
    const unsigned short* bp;
    float bias;
    if (type == 2) {
      int pnt = wave * 3 + nt;
      bp = pwp + ((size_t)(pnt * 3) * 64 + lane) * 8;
      bias = pb[pnt * 16 + l15];
    } else {
      int gnt = type * 12 + hh * 4 + nt;
      bp = qwp + (size_t)gnt * 1536 + lane * 8;
      bias = qb[type * 192 + hh * 64 + nt * 16 + l15];
    }
    bf16x8 b0 = *(const bf16x8*)(bp);
    bf16x8 b1v = *(const bf16x8*)(bp + 512);
    bf16x8 b2v = *(const bf16x8*)(bp + 1024);
#pragma unroll
    for (int mt = 0; mt < 4; ++mt) {
      f32x4 acc = {0.f, 0.f, 0.f, 0.f};
      acc = __builtin_amdgcn_mfma_f32_16x16x32_bf16(areg[mt][0], b0, acc, 0, 0, 0);
      acc = __builtin_amdgcn_mfma_f32_16x16x32_bf16(areg[mt][1], b1v, acc, 0, 0, 0);
      acc = __builtin_amdgcn_mfma_f32_16x16x32_bf16(areg[mt][2], b2v, acc, 0, 0, 0);
      if (type == 0) {
        float p0 = fmaxf(acc[0], acc[1]);
        float p1 = fmaxf(acc[2], acc[3]);
        float q0 = fmaxf(p0, __shfl_xor(p0, 32));
        float q1 = fmaxf(p1, __shfl_xor(p1, 32));
        unsigned int uq = pk2(q0 + bias, q1 + bias);
        if (quad < 2) {
          int p = mt * 4 + quad * 2;
          wbuf[wave][p][nt * 16 + l15] = (unsigned short)uq;
          wbuf[wave][p + 1][nt * 16 + l15] = (unsigned short)(uq >> 16);
        }
      } else if (type == 1) {
        int dglob = hh * 64 + nt * 16 + l15;
        int t0 = mt * 16 + quad * 4;
        unsigned int u01 = pk2(acc[0] + bias, acc[1] + bias);
        unsigned int u23 = pk2(acc[2] + bias, acc[3] + bias);
        kk[t0 + 0][dglob] = (unsigned short)u01;
        kk[t0 + 1][dglob] = (unsigned short)(u01 >> 16);
        kk[t0 + 2][dglob] = (unsigned short)u23;
        kk[t0 + 3][dglob] = (unsigned short)(u23 >> 16);
      } else {
        float p0 = fmaxf(acc[0], acc[1]);
        float p1 = fmaxf(acc[2], acc[3]);
        scr[nt][mt][0] = fmaxf(p0, __shfl_xor(p0, 32)) + bias;
        scr[nt][mt][1] = fmaxf(p1, __shfl_xor(p1, 32)) + bias;
      }
    }
  }
  __syncthreads();  // B1: K + pooled Q visible

  // ---- QK^T + softmax + P->wbuf, all BEFORE V phase (kills s4/ps liveness) --
  if (wave < 3) {
    int h = wave;
    bf16x8 aq0 = *(const bf16x8*)(&wbuf[wave][l15][quad * 8]);
    bf16x8 aq1 = *(const bf16x8*)(&wbuf[wave][l15][32 + quad * 8]);
    f32x4 s4[4];
#pragma unroll
    for (int kt = 0; kt < 4; ++kt) {
      bf16x8 bk0 = *(const bf16x8*)(&kk[kt * 16 + l15][h * 64 + quad * 8]);
      bf16x8 bk1 = *(const bf16x8*)(&kk[kt * 16 + l15][h * 64 + 32 + quad * 8]);
      f32x4 s = {0.f, 0.f, 0.f, 0.f};
      s = __builtin_amdgcn_mfma_f32_16x16x32_bf16(aq0, bk0, s, 0, 0, 0);
      s = __builtin_amdgcn_mfma_f32_16x16x32_bf16(aq1, bk1, s, 0, 0, 0);
      s4[kt] = s;
    }
    // in-register softmax over 64 keys; P overwrites pooled Q (wave-private)
#pragma unroll
    for (int r = 0; r < 4; ++r) {
      float ps0, ps1, ps2, ps3;
      float m = fmaxf(fmaxf(s4[0][r], s4[1][r]), fmaxf(s4[2][r], s4[3][r]));
#pragma unroll
      for (int o = 8; o; o >>= 1) m = fmaxf(m, __shfl_xor(m, o));
      ps0 = __expf((s4[0][r] - m) * 0.125f);
      ps1 = __expf((s4[1][r] - m) * 0.125f);
      ps2 = __expf((s4[2][r] - m) * 0.125f);
      ps3 = __expf((s4[3][r] - m) * 0.125f);
      float sm = ps0 + ps1 + ps2 + ps3;
#pragma unroll
      for (int o = 8; o; o >>= 1) sm += __shfl_xor(sm, o);
      float inv = __builtin_amdgcn_rcpf(sm);
      int row = quad * 4 + r;
      unsigned int u0 = pk2(ps0 * inv, ps1 * inv);
      unsigned int u1 = pk2(ps2 * inv, ps3 * inv);
      wbuf[wave][row][l15] = (unsigned short)u0;
      wbuf[wave][row][16 + l15] = (unsigned short)(u0 >> 16);
      wbuf[wave][row][32 + l15] = (unsigned short)u1;
      wbuf[wave][row][48 + l15] = (unsigned short)(u1 >> 16);
    }
  }
  __syncthreads();  // B1.5: all K reads done -> V may overwrite buf1

  // ---- Phase B: V GEMM (3 jobs/wave, all waves) into vT ----
#pragma unroll
  for (int vj = 0; vj < 3; ++vj) {
    int vidx = wave * 3 + vj;
    int hh = vidx >> 2, nt = vidx & 3;
    const unsigned short* bp =
        qwp + (size_t)(24 + hh * 4 + nt) * 1536 + lane * 8;
    bf16x8 b0 = *(const bf16x8*)(bp);
    bf16x8 b1v = *(const bf16x8*)(bp + 512);
    bf16x8 b2v = *(const bf16x8*)(bp + 1024);
    int dglob = hh * 64 + nt * 16 + l15;
    float bias = qb[384 + dglob];
#pragma unroll
    for (int mt = 0; mt < 4; ++mt) {
      f32x4 acc = {0.f, 0.f, 0.f, 0.f};
      acc = __builtin_amdgcn_mfma_f32_16x16x32_bf16(areg[mt][0], b0, acc, 0, 0, 0);
      acc = __builtin_amdgcn_mfma_f32_16x16x32_bf16(areg[mt][1], b1v, acc, 0, 0, 0);
      acc = __builtin_amdgcn_mfma_f32_16x16x32_bf16(areg[mt][2], b2v, acc, 0, 0, 0);
      int t0 = mt * 16 + quad * 4;
      u32x2 pk;
      pk[0] = pk2(acc[0] + bias, acc[1] + bias);
      pk[1] = pk2(acc[2] + bias, acc[3] + bias);
      *(u32x2*)(&vT[dglob][t0]) = pk;
    }
  }
  __syncthreads();  // B1.75: vT visible (P already in wbuf)

  // ---- PV ----
  f32x4 o4[4];
  if (wave < 3) {
    int h = wave;
    bf16x8 ap0 = *(const bf16x8*)(&wbuf[wave][l15][quad * 8]);
    bf16x8 ap1 = *(const bf16x8*)(&wbuf[wave][l15][32 + quad * 8]);
#pragma unroll
    for (int dt = 0; dt < 4; ++dt) {
      bf16x8 bv0 = *(const bf16x8*)(&vT[h * 64 + dt * 16 + l15][quad * 8]);
      bf16x8 bv1 = *(const bf16x8*)(&vT[h * 64 + dt * 16 + l15][32 + quad * 8]);
      f32x4 o = {0.f, 0.f, 0.f, 0.f};
      o = __builtin_amdgcn_mfma_f32_16x16x32_bf16(ap0, bv0, o, 0, 0, 0);
      o = __builtin_amdgcn_mfma_f32_16x16x32_bf16(ap1, bv1, o, 0, 0, 0);
      o4[dt] = o;
    }
  }
  __syncthreads();  // B2: V/wbuf reads done -> obb writable, wbuf dead -> sc

  // Pure stores: obb (waves 0..2) + shortcut from scr regs (quad<2 lanes)
  if (wave < 3) {
    int h = wave;
#pragma unroll
    for (int r = 0; r < 4; ++r) {
      int row = quad * 4 + r;
      unsigned int u0 = pk2(o4[0][r], o4[1][r]);
      unsigned int u1 = pk2(o4[2][r], o4[3][r]);
      kk[row][h * 64 + l15] = (unsigned short)u0;
      kk[row][h * 64 + 16 + l15] = (unsigned short)(u0 >> 16);
      kk[row][h * 64 + 32 + l15] = (unsigned short)u1;
      kk[row][h * 64 + 48 + l15] = (unsigned short)(u1 >> 16);
    }
  }
  if (quad < 2) {
#pragma unroll
    for (int nl = 0; nl < 3; ++nl) {
      int c = (wave * 3 + nl) * 16 + l15;
#pragma unroll
      for (int mt = 0; mt < 4; ++mt) {
        int p = mt * 4 + quad * 2;
        sc[p][c] = scr[nl][mt][0];
        sc[p + 1][c] = scr[nl][mt][1];
      }
    }
  }
  __syncthreads();  // B3: obb + shortcut readable

  // ---- attn_proj: O(16x192) @ aw + ab; y = shortcut + attn into sc ----
  bf16x8 ao[6];
#pragma unroll
  for (int ks = 0; ks < 6; ++ks)
    ao[ks] = *(const bf16x8*)(&kk[l15][ks * 32 + quad * 8]);
#pragma unroll
  for (int nl = 0; nl < 3; ++nl) {
    int ntl = wave * 3 + nl;
    const unsigned short* bp = awp + (size_t)ntl * 3072 + lane * 8;
    f32x4 acc = {0.f, 0.f, 0.f, 0.f};
#pragma unroll
    for (int ks = 0; ks < 6; ++ks) {
      bf16x8 bw = *(const bf16x8*)(bp + ks * 512);
      acc = __builtin_amdgcn_mfma_f32_16x16x32_bf16(ao[ks], bw, acc, 0, 0, 0);
    }
    int cc = ntl * 16 + l15;
    float bias = ab[cc];
#pragma unroll
    for (int r = 0; r < 4; ++r) {
      int p = quad * 4 + r;
      sc[p][cc] += acc[r] + bias;  // unique (p,cc) per thread
    }
  }
  __syncthreads();  // B4: y complete in sc

  // ---- LN2 on the 16 pooled tokens (16 lanes per token, 12 ch each) ----
  {
    int tt = wave * 4 + quad;  // 0..15
    const f32x4* y4 = (const f32x4*)(&sc[tt][l15 * 12]);
    f32x4 vv[3];
    vv[0] = y4[0]; vv[1] = y4[1]; vv[2] = y4[2];
    float s = 0.f;
#pragma unroll
    for (int i = 0; i < 3; ++i)
#pragma unroll
      for (int j = 0; j < 4; ++j) s += vv[i][j];
    s += __shfl_xor(s, 1);
    s += __shfl_xor(s, 2);
    s += __shfl_xor(s, 4);
    s += __shfl_xor(s, 8);
    float mean = s * (1.f / 192.f);
    float q = 0.f;
#pragma unroll
    for (int i = 0; i < 3; ++i)
#pragma unroll
      for (int j = 0; j < 4; ++j) {
        float d = vv[i][j] - mean;
        q += d * d;
      }
    q += __shfl_xor(q, 1);
    q += __shfl_xor(q, 2);
    q += __shfl_xor(q, 4);
    q += __shfl_xor(q, 8);
    float rstd = rsqrtf(q * (1.f / 192.f) + EPSV);
    const f32x4* g4 = (const f32x4*)(n2g + l15 * 12);
    const f32x4* b4 = (const f32x4*)(n2b + l15 * 12);
#pragma unroll
    for (int i = 0; i < 3; ++i) {
      f32x4 gg = g4[i], bb = b4[i];
      u32x2 w;
      w[0] = pk2((vv[i][0] - mean) * rstd * gg[0] + bb[0],
                 (vv[i][1] - mean) * rstd * gg[1] + bb[1]);
      w[1] = pk2((vv[i][2] - mean) * rstd * gg[2] + bb[2],
                 (vv[i][3] - mean) * rstd * gg[3] + bb[3]);
      *(u32x2*)(&yn[tt][l15 * 12 + i * 4]) = w;
    }
  }
  __syncthreads();  // B5: yn ready

  // ---- MLP: 16x192 -> 768 (gelu) -> 192, 2 hidden chunks of 384 ----
  bf16x8 ar[6];
#pragma unroll
  for (int ks = 0; ks < 6; ++ks)
    ar[ks] = *(const bf16x8*)(&yn[l15][ks * 32 + quad * 8]);

  f32x4 acc2[3];
#pragma unroll
  for (int nl = 0; nl < 3; ++nl) acc2[nl] = (f32x4){0.f, 0.f, 0.f, 0.f};

#pragma unroll
  for (int c = 0; c < 2; ++c) {
    // w1: 6 col-tiles per wave covering 96 cols of this 384-chunk
#pragma unroll
    for (int nl = 0; nl < 6; ++nl) {
      int gnt = c * 24 + wave * 6 + nl;
      const unsigned short* bp = w1p + ((size_t)(gnt * 6) * 64 + lane) * 8;
      f32x4 t0 = {0.f, 0.f, 0.f, 0.f};
#pragma unroll
      for (int ks = 0; ks < 6; ++ks) {
        bf16x8 bw = *(const bf16x8*)(bp + ks * 512);
        t0 = __builtin_amdgcn_mfma_f32_16x16x32_bf16(ar[ks], bw, t0, 0, 0, 0);
      }
      int lcol = wave * 96 + nl * 16 + l15;
      float bias = b1[c * 384 + lcol];
      unsigned int u0 = pk2(fast_gelu(t0[0] + bias), fast_gelu(t0[1] + bias));
      unsigned int u1 = pk2(fast_gelu(t0[2] + bias), fast_gelu(t0[3] + bias));
      hls[quad * 4 + 0][lcol] = (unsigned short)u0;
      hls[quad * 4 + 1][lcol] = (unsigned short)(u0 >> 16);
      hls[quad * 4 + 2][lcol] = (unsigned short)u1;
      hls[quad * 4 + 3][lcol] = (unsigned short)(u1 >> 16);
    }
    __syncthreads();  // hls chunk ready
    // w2: consume 384-wide hidden in two 6-frag groups (register cap)
#pragma unroll
    for (int g = 0; g < 2; ++g) {
      bf16x8 hr[6];
#pragma unroll
      for (int ks = 0; ks < 6; ++ks)
        hr[ks] = *(const bf16x8*)(&hls[l15][(g * 6 + ks) * 32 + quad * 8]);
#pragma unroll
      for (int nl = 0; nl < 3; ++nl) {
        int nt2 = wave * 3 + nl;
        const unsigned short* bp =
            w2p + ((size_t)(nt2 * 24 + c * 12 + g * 6) * 64 + lane) * 8;
#pragma unroll
        for (int ks = 0; ks < 6; ++ks) {
          bf16x8 bw = *(const bf16x8*)(bp + ks * 512);
          acc2[nl] =
              __builtin_amdgcn_mfma_f32_16x16x32_bf16(hr[ks], bw, acc2[nl], 0, 0, 0);
        }
      }
    }
    if (c == 0) __syncthreads();  // hls readers done -> chunk 1 may overwrite
  }

  // ---- epilogue: out = y + mlp + b2, pure store ----
#pragma unroll
  for (int nl = 0; nl < 3; ++nl) {
    int col = (wave * 3 + nl) * 16 + l15;
    float bias = b2[col];
#pragma unroll
    for (int r = 0; r < 4; ++r) {
      int p = quad * 4 + r;
      int hp = nh * 4 + (p >> 2), wp2 = nw * 4 + (p & 3);
      size_t oi = ((size_t)((b * 128 + hp) * 128 + wp2)) * 192 + col;
      out[oi] = sc[p][col] + acc2[nl][r] + bias;
    }
  }
}

extern "C" void kernel_launch(void* const* d_in, const int* in_sizes, int n_in,
                              void* d_out, int out_size, void* d_ws,
                              size_t ws_size, hipStream_t stream) {
  const float* x = (const float*)d_in[0];
  const float* n1g = (const float*)d_in[1];
  const float* n1b = (const float*)d_in[2];
  const float* pw = (const float*)d_in[3];
  const float* pb = (const float*)d_in[4];
  const float* qw = (const float*)d_in[5];
  const float* qb = (const float*)d_in[6];
  const float* aw = (const float*)d_in[7];
  const float* ab = (const float*)d_in[8];
  const float* n2g = (const float*)d_in[9];
  const float* n2b = (const float*)d_in[10];
  const float* w1 = (const float*)d_in[11];
  const float* b1 = (const float*)d_in[12];
  const float* w2 = (const float*)d_in[13];
  const float* b2 = (const float*)d_in[14];
  float* out = (float*)d_out;

  char* wsb = (char*)d_ws;
  unsigned short* qwp = (unsigned short*)wsb;               //    110,592 B
  unsigned short* awp = (unsigned short*)(wsb + 110592);    //     73,728 B
  unsigned short* w1p = (unsigned short*)(wsb + 184320);    //    294,912 B
  unsigned short* w2p = (unsigned short*)(wsb + 479232);    //    294,912 B
  unsigned short* pwp = (unsigned short*)(wsb + 774144);    //     36,864 B

  hipLaunchKernelGGL(k0_pack, dim3(198), dim3(256), 0, stream, qw, aw, w1, w2,
                     pw, qwp, awp, w1p, w2p, pwp);
  hipLaunchKernelGGL(k1234_fused, dim3(4096), dim3(256), 0, stream, x, n1g,
                     n1b, pwp, pb, qwp, qb, awp, ab, n2g, n2b, w1p, b1, w2p,
                     b2, out);
}

// Round 8
// 377.290 us; speedup vs baseline: 1.0894x; 1.0894x over previous
//
#include <hip/hip_runtime.h>
#include <hip/hip_bf16.h>
#include <math.h>

#define EPSV 1e-6f

typedef __attribute__((ext_vector_type(8))) short bf16x8;
typedef __attribute__((ext_vector_type(4))) float f32x4;
typedef __attribute__((ext_vector_type(4))) unsigned short u16x4;
typedef __attribute__((ext_vector_type(2))) unsigned int u32x2;

__device__ inline float bf2f(unsigned short u) {
  union { unsigned int i; float f; } v;
  v.i = ((unsigned int)u) << 16;
  return v.f;
}
// RNE bf16 round, no NaN path (all values finite here)
__device__ inline unsigned short f2bf(float f) {
  unsigned int u = __builtin_bit_cast(unsigned int, f);
  u += 0x7FFFu + ((u >> 16) & 1u);
  return (unsigned short)(u >> 16);
}
// HW packed f32x2 -> bf16x2 (RNE), 1 VALU op for 2 values
__device__ inline unsigned int pk2(float lo, float hi) {
  unsigned int r;
  asm("v_cvt_pk_bf16_f32 %0, %1, %2" : "=v"(r) : "v"(lo), "v"(hi));
  return r;
}
// tanh-GELU via exp + hw rcp (no div sequence)
__device__ inline float fast_gelu(float v) {
  float u = 1.5957691216057308f * (v + 0.044715f * v * v * v);
  float t = __expf(-u);
  return v * __builtin_amdgcn_rcpf(1.f + t);
}

// ---- Kernel 0: pack all weights into MFMA B-fragment layout (bf16) ----
// B-frag: [ntile][kstep][lane][8], n=ntile*16+(lane&15), k=kstep*32+(lane>>4)*8+j
__global__ __launch_bounds__(256) void k0_pack(
    const float* __restrict__ qw, const float* __restrict__ aw,
    const float* __restrict__ w1, const float* __restrict__ w2,
    const float* __restrict__ pw, unsigned short* __restrict__ qwp,
    unsigned short* __restrict__ awp, unsigned short* __restrict__ w1p,
    unsigned short* __restrict__ w2p, unsigned short* __restrict__ pwp) {
  int idx = blockIdx.x * 256 + threadIdx.x;
  int lane = idx & 63;
  int l15 = lane & 15, quad = lane >> 4;
  if (idx < 6912) {
    int fi = idx >> 6;
    int ntile = fi / 3, kstep = fi - ntile * 3;
    int n = ntile * 16 + l15, k0 = kstep * 32 + quad * 8;
#pragma unroll
    for (int j = 0; j < 8; ++j)
      qwp[(size_t)idx * 8 + j] = f2bf(qw[(size_t)(k0 + j) * 576 + n]);
  } else if (idx < 11520) {
    int i2 = idx - 6912;
    int fi = i2 >> 6;
    int ntile = fi / 6, kstep = fi - ntile * 6;
    int n = ntile * 16 + l15, k0 = kstep * 32 + quad * 8;
#pragma unroll
    for (int j = 0; j < 8; ++j)
      awp[(size_t)i2 * 8 + j] = f2bf(aw[(size_t)(k0 + j) * 192 + n]);
  } else if (idx < 29952) {
    int i3 = idx - 11520;
    int fi = i3 >> 6;
    int ntile = fi / 6, kstep = fi - ntile * 6;
    int n = ntile * 16 + l15, k0 = kstep * 32 + quad * 8;
#pragma unroll
    for (int j = 0; j < 8; ++j)
      w1p[(size_t)i3 * 8 + j] = f2bf(w1[(size_t)(k0 + j) * 768 + n]);
  } else if (idx < 48384) {
    int i4 = idx - 29952;
    int fi = i4 >> 6;
    int ntile = fi / 24, kstep = fi - ntile * 24;
    int n = ntile * 16 + l15, k0 = kstep * 32 + quad * 8;
#pragma unroll
    for (int j = 0; j < 8; ++j)
      w2p[(size_t)i4 * 8 + j] = f2bf(w2[(size_t)(k0 + j) * 192 + n]);
  } else if (idx < 50688) {
    int i5 = idx - 48384;
    int fi = i5 >> 6;
    int ntile = fi / 3, kstep = fi - ntile * 3;
    int n = ntile * 16 + l15, k0 = kstep * 32 + quad * 8;
#pragma unroll
    for (int j = 0; j < 8; ++j)
      pwp[(size_t)i5 * 8 + j] = f2bf(pw[(size_t)(k0 + j) * 192 + n]);
  }
}

// -- Kernel 1234: whole block fused (round-6 structure + two safe tweaks).
// LDS (40,192 B; x4 = 160,768 <= 163,840 -> 4 blocks/CU):
//   buf1 @0      (27,648): xn -> K[64][200] -> V^T[192][72] -> obb[16][200]
//                          (+yn @6400, hls[16][392] @12800 after V dead)
//   scwb @27,648 (12,544): wbuf[3][16][72] (Q->P, dead after PV)
//                          then sc[16][196] f32 (shortcut -> y; stride 196
//                          breaks the 768B same-bank 4-way conflict)
// Register discipline (rounds 4/7 lesson): NOTHING is carried in registers
// across the attention middle under (256,4). proj runs after PV (wbuf dead)
// writing sc directly; softmax runs before V so s4/ps die early.
__global__ __launch_bounds__(256, 4) void k1234_fused(
    const float* __restrict__ x, const float* __restrict__ n1g,
    const float* __restrict__ n1b, const unsigned short* __restrict__ pwp,
    const float* __restrict__ pb, const unsigned short* __restrict__ qwp,
    const float* __restrict__ qb, const unsigned short* __restrict__ awp,
    const float* __restrict__ ab, const float* __restrict__ n2g,
    const float* __restrict__ n2b, const unsigned short* __restrict__ w1p,
    const float* __restrict__ b1, const unsigned short* __restrict__ w2p,
    const float* __restrict__ b2, float* __restrict__ out) {
  __shared__ __align__(16) unsigned char smem[40192];
  unsigned short (*kk)[200] = (unsigned short (*)[200])smem;   // xn/K/obb
  unsigned short (*vT)[72] = (unsigned short (*)[72])smem;     // V^T (after B1.5)
  unsigned short (*yn)[200] = (unsigned short (*)[200])(smem + 6400);
  unsigned short (*hls)[392] = (unsigned short (*)[392])(smem + 12800);
  unsigned short (*wbuf)[16][72] =
      (unsigned short (*)[16][72])(smem + 27648);
  float (*sc)[196] = (float (*)[196])(smem + 27648);  // aliases wbuf (later)

  int tid = threadIdx.x, wave = tid >> 6, lane = tid & 63;
  int wi = blockIdx.x;
  int b = wi >> 10, nh = (wi >> 5) & 31, nw = wi & 31;
  int grow0 = nh * 8, gcol0 = nw * 8;
  int l15 = lane & 15, quad = lane >> 4;

  // ---- LN1: token tt (0..63) handled by 4 threads (sub 0..3) ----
  {
    int tt = tid >> 2, sub = tid & 3;
    int rr = tt >> 3, cc = tt & 7;
    size_t tok = (size_t)((b * 256 + grow0 + rr) * 256 + gcol0 + cc);
    const f32x4* xr4 = (const f32x4*)(x + tok * 96 + sub * 24);
    f32x4 v[6];
#pragma unroll
    for (int i = 0; i < 6; ++i) v[i] = xr4[i];
    float s = 0.f;
#pragma unroll
    for (int i = 0; i < 6; ++i)
#pragma unroll
      for (int j = 0; j < 4; ++j) s += v[i][j];
    s += __shfl_xor(s, 1);
    s += __shfl_xor(s, 2);
    float mean = s * (1.f / 96.f);
    float q = 0.f;
#pragma unroll
    for (int i = 0; i < 6; ++i)
#pragma unroll
      for (int j = 0; j < 4; ++j) {
        float d = v[i][j] - mean;
        q += d * d;
      }
    q += __shfl_xor(q, 1);
    q += __shfl_xor(q, 2);
    float rstd = rsqrtf(q * (1.f / 96.f) + EPSV);
    const f32x4* g4 = (const f32x4*)(n1g + sub * 24);
    const f32x4* b4 = (const f32x4*)(n1b + sub * 24);
#pragma unroll
    for (int i = 0; i < 6; ++i) {
      f32x4 gg = g4[i], bb = b4[i];
      u32x2 w;
      w[0] = pk2((v[i][0] - mean) * rstd * gg[0] + bb[0],
                 (v[i][1] - mean) * rstd * gg[1] + bb[1]);
      w[1] = pk2((v[i][2] - mean) * rstd * gg[2] + bb[2],
                 (v[i][3] - mean) * rstd * gg[3] + bb[3]);
      *(u32x2*)(&kk[tt][sub * 24 + i * 4]) = w;  // xn aliased into kk
    }
  }
  __syncthreads();  // S1: xn visible

  // A-frags (xw 64x96) from LDS; m = token index (row-major in window)
  bf16x8 areg[4][3];
#pragma unroll
  for (int mt = 0; mt < 4; ++mt)
#pragma unroll
    for (int ks = 0; ks < 3; ++ks)
      areg[mt][ks] = *(const bf16x8*)(&kk[mt * 16 + l15][ks * 32 + quad * 8]);
  __syncthreads();  // S2: xn dead -> kk writable (K)

  // ---- Phase A: Q + K GEMM (6 jobs/wave: w<3 -> 4Q+2K; w3 -> 6K) ----
#pragma unroll
  for (int aj = 0; aj < 6; ++aj) {
    int type, hh, nt;
    if (wave < 3) {
      if (aj < 4) { type = 0; hh = wave; nt = aj; }
      else { int kidx = wave * 2 + (aj - 4); type = 1; hh = kidx >> 2; nt = kidx & 3; }
    } else {
      int kidx = 6 + aj; type = 1; hh = kidx >> 2; nt = kidx & 3;
    }
    int gnt = type * 12 + hh * 4 + nt;
    const unsigned short* bp = qwp + (size_t)gnt * 1536 + lane * 8;
    bf16x8 b0 = *(const bf16x8*)(bp);
    bf16x8 b1v = *(const bf16x8*)(bp + 512);
    bf16x8 b2v = *(const bf16x8*)(bp + 1024);
    int dloc = nt * 16 + l15;
    int dglob = hh * 64 + dloc;
    float bias = qb[type * 192 + dglob];
#pragma unroll
    for (int mt = 0; mt < 4; ++mt) {
      f32x4 acc = {0.f, 0.f, 0.f, 0.f};
      acc = __builtin_amdgcn_mfma_f32_16x16x32_bf16(areg[mt][0], b0, acc, 0, 0, 0);
      acc = __builtin_amdgcn_mfma_f32_16x16x32_bf16(areg[mt][1], b1v, acc, 0, 0, 0);
      acc = __builtin_amdgcn_mfma_f32_16x16x32_bf16(areg[mt][2], b2v, acc, 0, 0, 0);
      if (type == 0) {
        float p0 = fmaxf(acc[0], acc[1]);
        float p1 = fmaxf(acc[2], acc[3]);
        float q0 = fmaxf(p0, __shfl_xor(p0, 32));
        float q1 = fmaxf(p1, __shfl_xor(p1, 32));
        unsigned int uq = pk2(q0 + bias, q1 + bias);
        if (quad < 2) {
          int p = mt * 4 + quad * 2;
          wbuf[wave][p][dloc] = (unsigned short)uq;
          wbuf[wave][p + 1][dloc] = (unsigned short)(uq >> 16);
        }
      } else {
        int t0 = mt * 16 + quad * 4;
        unsigned int u01 = pk2(acc[0] + bias, acc[1] + bias);
        unsigned int u23 = pk2(acc[2] + bias, acc[3] + bias);
        kk[t0 + 0][dglob] = (unsigned short)u01;
        kk[t0 + 1][dglob] = (unsigned short)(u01 >> 16);
        kk[t0 + 2][dglob] = (unsigned short)u23;
        kk[t0 + 3][dglob] = (unsigned short)(u23 >> 16);
      }
    }
  }
  __syncthreads();  // B1: K + pooled Q visible

  // ---- QK^T + softmax + P->wbuf, all BEFORE V phase (kills s4/ps liveness) --
  if (wave < 3) {
    int h = wave;
    bf16x8 aq0 = *(const bf16x8*)(&wbuf[wave][l15][quad * 8]);
    bf16x8 aq1 = *(const bf16x8*)(&wbuf[wave][l15][32 + quad * 8]);
    f32x4 s4[4];
#pragma unroll
    for (int kt = 0; kt < 4; ++kt) {
      bf16x8 bk0 = *(const bf16x8*)(&kk[kt * 16 + l15][h * 64 + quad * 8]);
      bf16x8 bk1 = *(const bf16x8*)(&kk[kt * 16 + l15][h * 64 + 32 + quad * 8]);
      f32x4 s = {0.f, 0.f, 0.f, 0.f};
      s = __builtin_amdgcn_mfma_f32_16x16x32_bf16(aq0, bk0, s, 0, 0, 0);
      s = __builtin_amdgcn_mfma_f32_16x16x32_bf16(aq1, bk1, s, 0, 0, 0);
      s4[kt] = s;
    }
    // in-register softmax over 64 keys; P overwrites pooled Q (wave-private)
#pragma unroll
    for (int r = 0; r < 4; ++r) {
      float m = fmaxf(fmaxf(s4[0][r], s4[1][r]), fmaxf(s4[2][r], s4[3][r]));
#pragma unroll
      for (int o = 8; o; o >>= 1) m = fmaxf(m, __shfl_xor(m, o));
      float ps0 = __expf((s4[0][r] - m) * 0.125f);
      float ps1 = __expf((s4[1][r] - m) * 0.125f);
      float ps2 = __expf((s4[2][r] - m) * 0.125f);
      float ps3 = __expf((s4[3][r] - m) * 0.125f);
      float sm = ps0 + ps1 + ps2 + ps3;
#pragma unroll
      for (int o = 8; o; o >>= 1) sm += __shfl_xor(sm, o);
      float inv = __builtin_amdgcn_rcpf(sm);
      int row = quad * 4 + r;
      unsigned int u0 = pk2(ps0 * inv, ps1 * inv);
      unsigned int u1 = pk2(ps2 * inv, ps3 * inv);
      wbuf[wave][row][l15] = (unsigned short)u0;
      wbuf[wave][row][16 + l15] = (unsigned short)(u0 >> 16);
      wbuf[wave][row][32 + l15] = (unsigned short)u1;
      wbuf[wave][row][48 + l15] = (unsigned short)(u1 >> 16);
    }
  }
  __syncthreads();  // B1.5: all K reads done -> V may overwrite buf1

  // ---- Phase B: V GEMM (3 jobs/wave, all waves) into vT ----
#pragma unroll
  for (int vj = 0; vj < 3; ++vj) {
    int vidx = wave * 3 + vj;
    int hh = vidx >> 2, nt = vidx & 3;
    const unsigned short* bp =
        qwp + (size_t)(24 + hh * 4 + nt) * 1536 + lane * 8;
    bf16x8 b0 = *(const bf16x8*)(bp);
    bf16x8 b1v = *(const bf16x8*)(bp + 512);
    bf16x8 b2v = *(const bf16x8*)(bp + 1024);
    int dglob = hh * 64 + nt * 16 + l15;
    float bias = qb[384 + dglob];
#pragma unroll
    for (int mt = 0; mt < 4; ++mt) {
      f32x4 acc = {0.f, 0.f, 0.f, 0.f};
      acc = __builtin_amdgcn_mfma_f32_16x16x32_bf16(areg[mt][0], b0, acc, 0, 0, 0);
      acc = __builtin_amdgcn_mfma_f32_16x16x32_bf16(areg[mt][1], b1v, acc, 0, 0, 0);
      acc = __builtin_amdgcn_mfma_f32_16x16x32_bf16(areg[mt][2], b2v, acc, 0, 0, 0);
      int t0 = mt * 16 + quad * 4;
      u32x2 pk;
      pk[0] = pk2(acc[0] + bias, acc[1] + bias);
      pk[1] = pk2(acc[2] + bias, acc[3] + bias);
      *(u32x2*)(&vT[dglob][t0]) = pk;
    }
  }
  __syncthreads();  // B1.75: vT visible (P already in wbuf)

  // ---- PV ----
  f32x4 o4[4];
  if (wave < 3) {
    int h = wave;
    bf16x8 ap0 = *(const bf16x8*)(&wbuf[wave][l15][quad * 8]);
    bf16x8 ap1 = *(const bf16x8*)(&wbuf[wave][l15][32 + quad * 8]);
#pragma unroll
    for (int dt = 0; dt < 4; ++dt) {
      bf16x8 bv0 = *(const bf16x8*)(&vT[h * 64 + dt * 16 + l15][quad * 8]);
      bf16x8 bv1 = *(const bf16x8*)(&vT[h * 64 + dt * 16 + l15][32 + quad * 8]);
      f32x4 o = {0.f, 0.f, 0.f, 0.f};
      o = __builtin_amdgcn_mfma_f32_16x16x32_bf16(ap0, bv0, o, 0, 0, 0);
      o = __builtin_amdgcn_mfma_f32_16x16x32_bf16(ap1, bv1, o, 0, 0, 0);
      o4[dt] = o;
    }
  }
  __syncthreads();  // B2: V/wbuf reads done -> obb writable, wbuf dead -> sc

  // obb (waves 0..2)
  if (wave < 3) {
    int h = wave;
#pragma unroll
    for (int r = 0; r < 4; ++r) {
      int row = quad * 4 + r;
      unsigned int u0 = pk2(o4[0][r], o4[1][r]);
      unsigned int u1 = pk2(o4[2][r], o4[3][r]);
      kk[row][h * 64 + l15] = (unsigned short)u0;
      kk[row][h * 64 + 16 + l15] = (unsigned short)(u0 >> 16);
      kk[row][h * 64 + 32 + l15] = (unsigned short)u1;
      kk[row][h * 64 + 48 + l15] = (unsigned short)(u1 >> 16);
    }
  }
  // ---- proj + maxpool2x2 -> shortcut straight into sc (wbuf now dead) ----
  // Last use of areg; no register array carried across the attention middle.
#pragma unroll
  for (int nl = 0; nl < 3; ++nl) {
    int nt = wave * 3 + nl;
    const unsigned short* bp = pwp + ((size_t)(nt * 3) * 64 + lane) * 8;
    bf16x8 b0 = *(const bf16x8*)(bp);
    bf16x8 b1v = *(const bf16x8*)(bp + 512);
    bf16x8 b2v = *(const bf16x8*)(bp + 1024);
    int c = nt * 16 + l15;
    float bias = pb[c];
#pragma unroll
    for (int mt = 0; mt < 4; ++mt) {
      f32x4 acc = {0.f, 0.f, 0.f, 0.f};
      acc = __builtin_amdgcn_mfma_f32_16x16x32_bf16(areg[mt][0], b0, acc, 0, 0, 0);
      acc = __builtin_amdgcn_mfma_f32_16x16x32_bf16(areg[mt][1], b1v, acc, 0, 0, 0);
      acc = __builtin_amdgcn_mfma_f32_16x16x32_bf16(areg[mt][2], b2v, acc, 0, 0, 0);
      float p0 = fmaxf(acc[0], acc[1]);
      float p1 = fmaxf(acc[2], acc[3]);
      float q0 = fmaxf(p0, __shfl_xor(p0, 32)) + bias;
      float q1 = fmaxf(p1, __shfl_xor(p1, 32)) + bias;
      if (quad < 2) {
        int p = mt * 4 + quad * 2;
        sc[p][c] = q0;
        sc[p + 1][c] = q1;
      }
    }
  }
  __syncthreads();  // B3: obb + shortcut readable

  // ---- attn_proj: O(16x192) @ aw + ab; y = shortcut + attn into sc ----
  bf16x8 ao[6];
#pragma unroll
  for (int ks = 0; ks < 6; ++ks)
    ao[ks] = *(const bf16x8*)(&kk[l15][ks * 32 + quad * 8]);
#pragma unroll
  for (int nl = 0; nl < 3; ++nl) {
    int ntl = wave * 3 + nl;
    const unsigned short* bp = awp + (size_t)ntl * 3072 + lane * 8;
    f32x4 acc = {0.f, 0.f, 0.f, 0.f};
#pragma unroll
    for (int ks = 0; ks < 6; ++ks) {
      bf16x8 bw = *(const bf16x8*)(bp + ks * 512);
      acc = __builtin_amdgcn_mfma_f32_16x16x32_bf16(ao[ks], bw, acc, 0, 0, 0);
    }
    int cc = ntl * 16 + l15;
    float bias = ab[cc];
#pragma unroll
    for (int r = 0; r < 4; ++r) {
      int p = quad * 4 + r;
      sc[p][cc] += acc[r] + bias;  // unique (p,cc) per thread
    }
  }
  __syncthreads();  // B4: y complete in sc

  // ---- LN2 on the 16 pooled tokens (16 lanes per token, 12 ch each) ----
  {
    int tt = wave * 4 + quad;  // 0..15
    const f32x4* y4 = (const f32x4*)(&sc[tt][l15 * 12]);
    f32x4 vv[3];
    vv[0] = y4[0]; vv[1] = y4[1]; vv[2] = y4[2];
    float s = 0.f;
#pragma unroll
    for (int i = 0; i < 3; ++i)
#pragma unroll
      for (int j = 0; j < 4; ++j) s += vv[i][j];
    s += __shfl_xor(s, 1);
    s += __shfl_xor(s, 2);
    s += __shfl_xor(s, 4);
    s += __shfl_xor(s, 8);
    float mean = s * (1.f / 192.f);
    float q = 0.f;
#pragma unroll
    for (int i = 0; i < 3; ++i)
#pragma unroll
      for (int j = 0; j < 4; ++j) {
        float d = vv[i][j] - mean;
        q += d * d;
      }
    q += __shfl_xor(q, 1);
    q += __shfl_xor(q, 2);
    q += __shfl_xor(q, 4);
    q += __shfl_xor(q, 8);
    float rstd = rsqrtf(q * (1.f / 192.f) + EPSV);
    const f32x4* g4 = (const f32x4*)(n2g + l15 * 12);
    const f32x4* b4 = (const f32x4*)(n2b + l15 * 12);
#pragma unroll
    for (int i = 0; i < 3; ++i) {
      f32x4 gg = g4[i], bb = b4[i];
      u32x2 w;
      w[0] = pk2((vv[i][0] - mean) * rstd * gg[0] + bb[0],
                 (vv[i][1] - mean) * rstd * gg[1] + bb[1]);
      w[1] = pk2((vv[i][2] - mean) * rstd * gg[2] + bb[2],
                 (vv[i][3] - mean) * rstd * gg[3] + bb[3]);
      *(u32x2*)(&yn[tt][l15 * 12 + i * 4]) = w;
    }
  }
  __syncthreads();  // B5: yn ready

  // ---- MLP: 16x192 -> 768 (gelu) -> 192, 2 hidden chunks of 384 ----
  bf16x8 ar[6];
#pragma unroll
  for (int ks = 0; ks < 6; ++ks)
    ar[ks] = *(const bf16x8*)(&yn[l15][ks * 32 + quad * 8]);

  f32x4 acc2[3];
#pragma unroll
  for (int nl = 0; nl < 3; ++nl) acc2[nl] = (f32x4){0.f, 0.f, 0.f, 0.f};

#pragma unroll
  for (int c = 0; c < 2; ++c) {
    // w1: 6 col-tiles per wave covering 96 cols of this 384-chunk
#pragma unroll
    for (int nl = 0; nl < 6; ++nl) {
      int gnt = c * 24 + wave * 6 + nl;
      const unsigned short* bp = w1p + ((size_t)(gnt * 6) * 64 + lane) * 8;
      f32x4 t0 = {0.f, 0.f, 0.f, 0.f};
#pragma unroll
      for (int ks = 0; ks < 6; ++ks) {
        bf16x8 bw = *(const bf16x8*)(bp + ks * 512);
        t0 = __builtin_amdgcn_mfma_f32_16x16x32_bf16(ar[ks], bw, t0, 0, 0, 0);
      }
      int lcol = wave * 96 + nl * 16 + l15;
      float bias = b1[c * 384 + lcol];
      unsigned int u0 = pk2(fast_gelu(t0[0] + bias), fast_gelu(t0[1] + bias));
      unsigned int u1 = pk2(fast_gelu(t0[2] + bias), fast_gelu(t0[3] + bias));
      hls[quad * 4 + 0][lcol] = (unsigned short)u0;
      hls[quad * 4 + 1][lcol] = (unsigned short)(u0 >> 16);
      hls[quad * 4 + 2][lcol] = (unsigned short)u1;
      hls[quad * 4 + 3][lcol] = (unsigned short)(u1 >> 16);
    }
    __syncthreads();  // hls chunk ready
    // w2: consume 384-wide hidden in two 6-frag groups (register cap)
#pragma unroll
    for (int g = 0; g < 2; ++g) {
      bf16x8 hr[6];
#pragma unroll
      for (int ks = 0; ks < 6; ++ks)
        hr[ks] = *(const bf16x8*)(&hls[l15][(g * 6 + ks) * 32 + quad * 8]);
#pragma unroll
      for (int nl = 0; nl < 3; ++nl) {
        int nt2 = wave * 3 + nl;
        const unsigned short* bp =
            w2p + ((size_t)(nt2 * 24 + c * 12 + g * 6) * 64 + lane) * 8;
#pragma unroll
        for (int ks = 0; ks < 6; ++ks) {
          bf16x8 bw = *(const bf16x8*)(bp + ks * 512);
          acc2[nl] =
              __builtin_amdgcn_mfma_f32_16x16x32_bf16(hr[ks], bw, acc2[nl], 0, 0, 0);
        }
      }
    }
    if (c == 0) __syncthreads();  // hls readers done -> chunk 1 may overwrite
  }

  // ---- epilogue: out = y + mlp + b2, pure store ----
#pragma unroll
  for (int nl = 0; nl < 3; ++nl) {
    int col = (wave * 3 + nl) * 16 + l15;
    float bias = b2[col];
#pragma unroll
    for (int r = 0; r < 4; ++r) {
      int p = quad * 4 + r;
      int hp = nh * 4 + (p >> 2), wp2 = nw * 4 + (p & 3);
      size_t oi = ((size_t)((b * 128 + hp) * 128 + wp2)) * 192 + col;
      out[oi] = sc[p][col] + acc2[nl][r] + bias;
    }
  }
}

extern "C" void kernel_launch(void* const* d_in, const int* in_sizes, int n_in,
                              void* d_out, int out_size, void* d_ws,
                              size_t ws_size, hipStream_t stream) {
  const float* x = (const float*)d_in[0];
  const float* n1g = (const float*)d_in[1];
  const float* n1b = (const float*)d_in[2];
  const float* pw = (const float*)d_in[3];
  const float* pb = (const float*)d_in[4];
  const float* qw = (const float*)d_in[5];
  const float* qb = (const float*)d_in[6];
  const float* aw = (const float*)d_in[7];
  const float* ab = (const float*)d_in[8];
  const float* n2g = (const float*)d_in[9];
  const float* n2b = (const float*)d_in[10];
  const float* w1 = (const float*)d_in[11];
  const float* b1 = (const float*)d_in[12];
  const float* w2 = (const float*)d_in[13];
  const float* b2 = (const float*)d_in[14];
  float* out = (float*)d_out;

  char* wsb = (char*)d_ws;
  unsigned short* qwp = (unsigned short*)wsb;               //    110,592 B
  unsigned short* awp = (unsigned short*)(wsb + 110592);    //     73,728 B
  unsigned short* w1p = (unsigned short*)(wsb + 184320);    //    294,912 B
  unsigned short* w2p = (unsigned short*)(wsb + 479232);    //    294,912 B
  unsigned short* pwp = (unsigned short*)(wsb + 774144);    //     36,864 B

  hipLaunchKernelGGL(k0_pack, dim3(198), dim3(256), 0, stream, qw, aw, w1, w2,
                     pw, qwp, awp, w1p, w2p, pwp);
  hipLaunchKernelGGL(k1234_fused, dim3(4096), dim3(256), 0, stream, x, n1g,
                     n1b, pwp, pb, qwp, qb, awp, ab, n2g, n2b, w1p, b1, w2p,
                     b2, out);
}

// Round 11
// 300.242 us; speedup vs baseline: 1.3690x; 1.2566x over previous
//
#include <hip/hip_runtime.h>
#include <hip/hip_bf16.h>
#include <math.h>

#define EPSV 1e-6f

typedef __attribute__((ext_vector_type(8))) short bf16x8;
typedef __attribute__((ext_vector_type(4))) float f32x4;
typedef __attribute__((ext_vector_type(4))) unsigned short u16x4;
typedef __attribute__((ext_vector_type(2))) unsigned int u32x2;

__device__ inline float bf2f(unsigned short u) {
  union { unsigned int i; float f; } v;
  v.i = ((unsigned int)u) << 16;
  return v.f;
}
// RNE bf16 round, no NaN path (all values finite here)
__device__ inline unsigned short f2bf(float f) {
  unsigned int u = __builtin_bit_cast(unsigned int, f);
  u += 0x7FFFu + ((u >> 16) & 1u);
  return (unsigned short)(u >> 16);
}
// HW packed f32x2 -> bf16x2 (RNE), 1 VALU op for 2 values
__device__ inline unsigned int pk2(float lo, float hi) {
  unsigned int r;
  asm("v_cvt_pk_bf16_f32 %0, %1, %2" : "=v"(r) : "v"(lo), "v"(hi));
  return r;
}
// tanh-GELU via exp + hw rcp (no div sequence)
__device__ inline float fast_gelu(float v) {
  float u = 1.5957691216057308f * (v + 0.044715f * v * v * v);
  float t = __expf(-u);
  return v * __builtin_amdgcn_rcpf(1.f + t);
}

// ---- Kernel 0: pack all weights into MFMA B-fragment layout (bf16) ----
// B-frag: [ntile][kstep][lane][8], n=ntile*16+(lane&15), k=kstep*32+(lane>>4)*8+j
__global__ __launch_bounds__(256) void k0_pack(
    const float* __restrict__ qw, const float* __restrict__ aw,
    const float* __restrict__ w1, const float* __restrict__ w2,
    const float* __restrict__ pw, unsigned short* __restrict__ qwp,
    unsigned short* __restrict__ awp, unsigned short* __restrict__ w1p,
    unsigned short* __restrict__ w2p, unsigned short* __restrict__ pwp) {
  int idx = blockIdx.x * 256 + threadIdx.x;
  int lane = idx & 63;
  int l15 = lane & 15, quad = lane >> 4;
  if (idx < 6912) {
    int fi = idx >> 6;
    int ntile = fi / 3, kstep = fi - ntile * 3;
    int n = ntile * 16 + l15, k0 = kstep * 32 + quad * 8;
#pragma unroll
    for (int j = 0; j < 8; ++j)
      qwp[(size_t)idx * 8 + j] = f2bf(qw[(size_t)(k0 + j) * 576 + n]);
  } else if (idx < 11520) {
    int i2 = idx - 6912;
    int fi = i2 >> 6;
    int ntile = fi / 6, kstep = fi - ntile * 6;
    int n = ntile * 16 + l15, k0 = kstep * 32 + quad * 8;
#pragma unroll
    for (int j = 0; j < 8; ++j)
      awp[(size_t)i2 * 8 + j] = f2bf(aw[(size_t)(k0 + j) * 192 + n]);
  } else if (idx < 29952) {
    int i3 = idx - 11520;
    int fi = i3 >> 6;
    int ntile = fi / 6, kstep = fi - ntile * 6;
    int n = ntile * 16 + l15, k0 = kstep * 32 + quad * 8;
#pragma unroll
    for (int j = 0; j < 8; ++j)
      w1p[(size_t)i3 * 8 + j] = f2bf(w1[(size_t)(k0 + j) * 768 + n]);
  } else if (idx < 48384) {
    int i4 = idx - 29952;
    int fi = i4 >> 6;
    int ntile = fi / 24, kstep = fi - ntile * 24;
    int n = ntile * 16 + l15, k0 = kstep * 32 + quad * 8;
#pragma unroll
    for (int j = 0; j < 8; ++j)
      w2p[(size_t)i4 * 8 + j] = f2bf(w2[(size_t)(k0 + j) * 192 + n]);
  } else if (idx < 50688) {
    int i5 = idx - 48384;
    int fi = i5 >> 6;
    int ntile = fi / 3, kstep = fi - ntile * 3;
    int n = ntile * 16 + l15, k0 = kstep * 32 + quad * 8;
#pragma unroll
    for (int j = 0; j < 8; ++j)
      pwp[(size_t)i5 * 8 + j] = f2bf(pw[(size_t)(k0 + j) * 192 + n]);
  }
}

// -- Kernel 1234: round-6 structure EXACTLY, + sc stride 192->196 only.
// LDS (40,192 B; x4 = 160,768 <= 163,840 -> 4 blocks/CU):
//   buf1 @0      (27,648): xn -> K[64][200] -> V^T[192][72] -> obb[16][200]
//                          (+yn @6400, hls @12800 after V dead)
//   scwb @27,648 (12,544): wbuf[3][16][72] (Q->P, dead after PV)
//                          then sc[16][196] f32 (stride 196 = 784B row:
//                          breaks the 768B same-bank 4-way conflict on
//                          attn_proj +=, proj store, epilogue read;
//                          784B = 49x16 keeps f32x4 LN2 reads aligned)
// Register discipline: nothing carried in regs across the attention middle;
// softmax before V; proj after PV. Small unrolled bodies (4-chunk MLP) keep
// the allocator at ~60 arch VGPRs (round-8's big region squeezed it to 56
// and serialized all load->MFMA chains).
__global__ __launch_bounds__(256, 4) void k1234_fused(
    const float* __restrict__ x, const float* __restrict__ n1g,
    const float* __restrict__ n1b, const unsigned short* __restrict__ pwp,
    const float* __restrict__ pb, const unsigned short* __restrict__ qwp,
    const float* __restrict__ qb, const unsigned short* __restrict__ awp,
    const float* __restrict__ ab, const float* __restrict__ n2g,
    const float* __restrict__ n2b, const unsigned short* __restrict__ w1p,
    const float* __restrict__ b1, const unsigned short* __restrict__ w2p,
    const float* __restrict__ b2, float* __restrict__ out) {
  __shared__ __align__(16) unsigned char smem[40192];
  unsigned short (*kk)[200] = (unsigned short (*)[200])smem;   // xn/K/obb
  unsigned short (*vT)[72] = (unsigned short (*)[72])smem;     // V^T (after B1.5)
  unsigned short (*yn)[200] = (unsigned short (*)[200])(smem + 6400);
  unsigned short (*hls)[200] = (unsigned short (*)[200])(smem + 12800);
  unsigned short (*wbuf)[16][72] =
      (unsigned short (*)[16][72])(smem + 27648);
  float (*sc)[196] = (float (*)[196])(smem + 27648);  // aliases wbuf (later)

  int tid = threadIdx.x, wave = tid >> 6, lane = tid & 63;
  int wi = blockIdx.x;
  int b = wi >> 10, nh = (wi >> 5) & 31, nw = wi & 31;
  int grow0 = nh * 8, gcol0 = nw * 8;
  int l15 = lane & 15, quad = lane >> 4;

  // ---- LN1: token tt (0..63) handled by 4 threads (sub 0..3) ----
  {
    int tt = tid >> 2, sub = tid & 3;
    int rr = tt >> 3, cc = tt & 7;
    size_t tok = (size_t)((b * 256 + grow0 + rr) * 256 + gcol0 + cc);
    const f32x4* xr4 = (const f32x4*)(x + tok * 96 + sub * 24);
    f32x4 v[6];
#pragma unroll
    for (int i = 0; i < 6; ++i) v[i] = xr4[i];
    float s = 0.f;
#pragma unroll
    for (int i = 0; i < 6; ++i)
#pragma unroll
      for (int j = 0; j < 4; ++j) s += v[i][j];
    s += __shfl_xor(s, 1);
    s += __shfl_xor(s, 2);
    float mean = s * (1.f / 96.f);
    float q = 0.f;
#pragma unroll
    for (int i = 0; i < 6; ++i)
#pragma unroll
      for (int j = 0; j < 4; ++j) {
        float d = v[i][j] - mean;
        q += d * d;
      }
    q += __shfl_xor(q, 1);
    q += __shfl_xor(q, 2);
    float rstd = rsqrtf(q * (1.f / 96.f) + EPSV);
    const f32x4* g4 = (const f32x4*)(n1g + sub * 24);
    const f32x4* b4 = (const f32x4*)(n1b + sub * 24);
#pragma unroll
    for (int i = 0; i < 6; ++i) {
      f32x4 gg = g4[i], bb = b4[i];
      u32x2 w;
      w[0] = pk2((v[i][0] - mean) * rstd * gg[0] + bb[0],
                 (v[i][1] - mean) * rstd * gg[1] + bb[1]);
      w[1] = pk2((v[i][2] - mean) * rstd * gg[2] + bb[2],
                 (v[i][3] - mean) * rstd * gg[3] + bb[3]);
      *(u32x2*)(&kk[tt][sub * 24 + i * 4]) = w;  // xn aliased into kk
    }
  }
  __syncthreads();  // S1: xn visible

  // A-frags (xw 64x96) from LDS; m = token index (row-major in window)
  bf16x8 areg[4][3];
#pragma unroll
  for (int mt = 0; mt < 4; ++mt)
#pragma unroll
    for (int ks = 0; ks < 3; ++ks)
      areg[mt][ks] = *(const bf16x8*)(&kk[mt * 16 + l15][ks * 32 + quad * 8]);
  __syncthreads();  // S2: xn dead -> kk writable (K)

  // ---- Phase A: Q + K GEMM (6 jobs/wave: w<3 -> 4Q+2K; w3 -> 6K) ----
#pragma unroll
  for (int aj = 0; aj < 6; ++aj) {
    int type, hh, nt;
    if (wave < 3) {
      if (aj < 4) { type = 0; hh = wave; nt = aj; }
      else { int kidx = wave * 2 + (aj - 4); type = 1; hh = kidx >> 2; nt = kidx & 3; }
    } else {
      int kidx = 6 + aj; type = 1; hh = kidx >> 2; nt = kidx & 3;
    }
    int gnt = type * 12 + hh * 4 + nt;
    const unsigned short* bp = qwp + (size_t)gnt * 1536 + lane * 8;
    bf16x8 b0 = *(const bf16x8*)(bp);
    bf16x8 b1v = *(const bf16x8*)(bp + 512);
    bf16x8 b2v = *(const bf16x8*)(bp + 1024);
    int dloc = nt * 16 + l15;
    int dglob = hh * 64 + dloc;
    float bias = qb[type * 192 + dglob];
#pragma unroll
    for (int mt = 0; mt < 4; ++mt) {
      f32x4 acc = {0.f, 0.f, 0.f, 0.f};
      acc = __builtin_amdgcn_mfma_f32_16x16x32_bf16(areg[mt][0], b0, acc, 0, 0, 0);
      acc = __builtin_amdgcn_mfma_f32_16x16x32_bf16(areg[mt][1], b1v, acc, 0, 0, 0);
      acc = __builtin_amdgcn_mfma_f32_16x16x32_bf16(areg[mt][2], b2v, acc, 0, 0, 0);
      if (type == 0) {
        float p0 = fmaxf(acc[0], acc[1]);
        float p1 = fmaxf(acc[2], acc[3]);
        float q0 = fmaxf(p0, __shfl_xor(p0, 32));
        float q1 = fmaxf(p1, __shfl_xor(p1, 32));
        unsigned int uq = pk2(q0 + bias, q1 + bias);
        if (quad < 2) {
          int p = mt * 4 + quad * 2;
          wbuf[wave][p][dloc] = (unsigned short)uq;
          wbuf[wave][p + 1][dloc] = (unsigned short)(uq >> 16);
        }
      } else {
        int t0 = mt * 16 + quad * 4;
        unsigned int u01 = pk2(acc[0] + bias, acc[1] + bias);
        unsigned int u23 = pk2(acc[2] + bias, acc[3] + bias);
        kk[t0 + 0][dglob] = (unsigned short)u01;
        kk[t0 + 1][dglob] = (unsigned short)(u01 >> 16);
        kk[t0 + 2][dglob] = (unsigned short)u23;
        kk[t0 + 3][dglob] = (unsigned short)(u23 >> 16);
      }
    }
  }
  __syncthreads();  // B1: K + pooled Q visible

  // ---- QK^T + softmax + P->wbuf, all BEFORE V phase (kills s4/ps liveness) --
  if (wave < 3) {
    int h = wave;
    bf16x8 aq0 = *(const bf16x8*)(&wbuf[wave][l15][quad * 8]);
    bf16x8 aq1 = *(const bf16x8*)(&wbuf[wave][l15][32 + quad * 8]);
    f32x4 s4[4];
#pragma unroll
    for (int kt = 0; kt < 4; ++kt) {
      bf16x8 bk0 = *(const bf16x8*)(&kk[kt * 16 + l15][h * 64 + quad * 8]);
      bf16x8 bk1 = *(const bf16x8*)(&kk[kt * 16 + l15][h * 64 + 32 + quad * 8]);
      f32x4 s = {0.f, 0.f, 0.f, 0.f};
      s = __builtin_amdgcn_mfma_f32_16x16x32_bf16(aq0, bk0, s, 0, 0, 0);
      s = __builtin_amdgcn_mfma_f32_16x16x32_bf16(aq1, bk1, s, 0, 0, 0);
      s4[kt] = s;
    }
    // in-register softmax over 64 keys; P overwrites pooled Q (wave-private)
#pragma unroll
    for (int r = 0; r < 4; ++r) {
      float m = fmaxf(fmaxf(s4[0][r], s4[1][r]), fmaxf(s4[2][r], s4[3][r]));
#pragma unroll
      for (int o = 8; o; o >>= 1) m = fmaxf(m, __shfl_xor(m, o));
      float ps0 = __expf((s4[0][r] - m) * 0.125f);
      float ps1 = __expf((s4[1][r] - m) * 0.125f);
      float ps2 = __expf((s4[2][r] - m) * 0.125f);
      float ps3 = __expf((s4[3][r] - m) * 0.125f);
      float sm = ps0 + ps1 + ps2 + ps3;
#pragma unroll
      for (int o = 8; o; o >>= 1) sm += __shfl_xor(sm, o);
      float inv = __builtin_amdgcn_rcpf(sm);
      int row = quad * 4 + r;
      unsigned int u0 = pk2(ps0 * inv, ps1 * inv);
      unsigned int u1 = pk2(ps2 * inv, ps3 * inv);
      wbuf[wave][row][l15] = (unsigned short)u0;
      wbuf[wave][row][16 + l15] = (unsigned short)(u0 >> 16);
      wbuf[wave][row][32 + l15] = (unsigned short)u1;
      wbuf[wave][row][48 + l15] = (unsigned short)(u1 >> 16);
    }
  }
  __syncthreads();  // B1.5: all K reads done -> V may overwrite buf1

  // ---- Phase B: V GEMM (3 jobs/wave, all waves) into vT ----
#pragma unroll
  for (int vj = 0; vj < 3; ++vj) {
    int vidx = wave * 3 + vj;
    int hh = vidx >> 2, nt = vidx & 3;
    const unsigned short* bp =
        qwp + (size_t)(24 + hh * 4 + nt) * 1536 + lane * 8;
    bf16x8 b0 = *(const bf16x8*)(bp);
    bf16x8 b1v = *(const bf16x8*)(bp + 512);
    bf16x8 b2v = *(const bf16x8*)(bp + 1024);
    int dglob = hh * 64 + nt * 16 + l15;
    float bias = qb[384 + dglob];
#pragma unroll
    for (int mt = 0; mt < 4; ++mt) {
      f32x4 acc = {0.f, 0.f, 0.f, 0.f};
      acc = __builtin_amdgcn_mfma_f32_16x16x32_bf16(areg[mt][0], b0, acc, 0, 0, 0);
      acc = __builtin_amdgcn_mfma_f32_16x16x32_bf16(areg[mt][1], b1v, acc, 0, 0, 0);
      acc = __builtin_amdgcn_mfma_f32_16x16x32_bf16(areg[mt][2], b2v, acc, 0, 0, 0);
      int t0 = mt * 16 + quad * 4;
      u32x2 pk;
      pk[0] = pk2(acc[0] + bias, acc[1] + bias);
      pk[1] = pk2(acc[2] + bias, acc[3] + bias);
      *(u32x2*)(&vT[dglob][t0]) = pk;
    }
  }
  __syncthreads();  // B1.75: vT visible (P already in wbuf)

  // ---- PV ----
  f32x4 o4[4];
  if (wave < 3) {
    int h = wave;
    bf16x8 ap0 = *(const bf16x8*)(&wbuf[wave][l15][quad * 8]);
    bf16x8 ap1 = *(const bf16x8*)(&wbuf[wave][l15][32 + quad * 8]);
#pragma unroll
    for (int dt = 0; dt < 4; ++dt) {
      bf16x8 bv0 = *(const bf16x8*)(&vT[h * 64 + dt * 16 + l15][quad * 8]);
      bf16x8 bv1 = *(const bf16x8*)(&vT[h * 64 + dt * 16 + l15][32 + quad * 8]);
      f32x4 o = {0.f, 0.f, 0.f, 0.f};
      o = __builtin_amdgcn_mfma_f32_16x16x32_bf16(ap0, bv0, o, 0, 0, 0);
      o = __builtin_amdgcn_mfma_f32_16x16x32_bf16(ap1, bv1, o, 0, 0, 0);
      o4[dt] = o;
    }
  }
  __syncthreads();  // B2: V/wbuf reads done -> obb writable, wbuf dead -> sc

  // obb (waves 0..2)
  if (wave < 3) {
    int h = wave;
#pragma unroll
    for (int r = 0; r < 4; ++r) {
      int row = quad * 4 + r;
      unsigned int u0 = pk2(o4[0][r], o4[1][r]);
      unsigned int u1 = pk2(o4[2][r], o4[3][r]);
      kk[row][h * 64 + l15] = (unsigned short)u0;
      kk[row][h * 64 + 16 + l15] = (unsigned short)(u0 >> 16);
      kk[row][h * 64 + 32 + l15] = (unsigned short)u1;
      kk[row][h * 64 + 48 + l15] = (unsigned short)(u1 >> 16);
    }
  }
  // ---- proj + maxpool2x2 -> shortcut straight into sc (wbuf now dead) ----
  // Last use of areg; nothing carried across the attention middle.
#pragma unroll
  for (int nl = 0; nl < 3; ++nl) {
    int nt = wave * 3 + nl;
    const unsigned short* bp = pwp + ((size_t)(nt * 3) * 64 + lane) * 8;
    bf16x8 b0 = *(const bf16x8*)(bp);
    bf16x8 b1v = *(const bf16x8*)(bp + 512);
    bf16x8 b2v = *(const bf16x8*)(bp + 1024);
    int c = nt * 16 + l15;
    float bias = pb[c];
#pragma unroll
    for (int mt = 0; mt < 4; ++mt) {
      f32x4 acc = {0.f, 0.f, 0.f, 0.f};
      acc = __builtin_amdgcn_mfma_f32_16x16x32_bf16(areg[mt][0], b0, acc, 0, 0, 0);
      acc = __builtin_amdgcn_mfma_f32_16x16x32_bf16(areg[mt][1], b1v, acc, 0, 0, 0);
      acc = __builtin_amdgcn_mfma_f32_16x16x32_bf16(areg[mt][2], b2v, acc, 0, 0, 0);
      float p0 = fmaxf(acc[0], acc[1]);
      float p1 = fmaxf(acc[2], acc[3]);
      float q0 = fmaxf(p0, __shfl_xor(p0, 32)) + bias;
      float q1 = fmaxf(p1, __shfl_xor(p1, 32)) + bias;
      if (quad < 2) {
        int p = mt * 4 + quad * 2;
        sc[p][c] = q0;
        sc[p + 1][c] = q1;
      }
    }
  }
  __syncthreads();  // B3: obb + shortcut readable

  // ---- attn_proj: O(16x192) @ aw + ab; y = shortcut + attn into sc ----
  bf16x8 ao[6];
#pragma unroll
  for (int ks = 0; ks < 6; ++ks)
    ao[ks] = *(const bf16x8*)(&kk[l15][ks * 32 + quad * 8]);
#pragma unroll
  for (int nl = 0; nl < 3; ++nl) {
    int ntl = wave * 3 + nl;
    const unsigned short* bp = awp + (size_t)ntl * 3072 + lane * 8;
    f32x4 acc = {0.f, 0.f, 0.f, 0.f};
#pragma unroll
    for (int ks = 0; ks < 6; ++ks) {
      bf16x8 bw = *(const bf16x8*)(bp + ks * 512);
      acc = __builtin_amdgcn_mfma_f32_16x16x32_bf16(ao[ks], bw, acc, 0, 0, 0);
    }
    int cc = ntl * 16 + l15;
    float bias = ab[cc];
#pragma unroll
    for (int r = 0; r < 4; ++r) {
      int p = quad * 4 + r;
      sc[p][cc] += acc[r] + bias;  // unique (p,cc) per thread
    }
  }
  __syncthreads();  // B4: y complete in sc

  // ---- LN2 on the 16 pooled tokens (16 lanes per token, 12 ch each) ----
  {
    int tt = wave * 4 + quad;  // 0..15
    const f32x4* y4 = (const f32x4*)(&sc[tt][l15 * 12]);
    f32x4 vv[3];
    vv[0] = y4[0]; vv[1] = y4[1]; vv[2] = y4[2];
    float s = 0.f;
#pragma unroll
    for (int i = 0; i < 3; ++i)
#pragma unroll
      for (int j = 0; j < 4; ++j) s += vv[i][j];
    s += __shfl_xor(s, 1);
    s += __shfl_xor(s, 2);
    s += __shfl_xor(s, 4);
    s += __shfl_xor(s, 8);
    float mean = s * (1.f / 192.f);
    float q = 0.f;
#pragma unroll
    for (int i = 0; i < 3; ++i)
#pragma unroll
      for (int j = 0; j < 4; ++j) {
        float d = vv[i][j] - mean;
        q += d * d;
      }
    q += __shfl_xor(q, 1);
    q += __shfl_xor(q, 2);
    q += __shfl_xor(q, 4);
    q += __shfl_xor(q, 8);
    float rstd = rsqrtf(q * (1.f / 192.f) + EPSV);
    const f32x4* g4 = (const f32x4*)(n2g + l15 * 12);
    const f32x4* b4 = (const f32x4*)(n2b + l15 * 12);
#pragma unroll
    for (int i = 0; i < 3; ++i) {
      f32x4 gg = g4[i], bb = b4[i];
      u32x2 w;
      w[0] = pk2((vv[i][0] - mean) * rstd * gg[0] + bb[0],
                 (vv[i][1] - mean) * rstd * gg[1] + bb[1]);
      w[1] = pk2((vv[i][2] - mean) * rstd * gg[2] + bb[2],
                 (vv[i][3] - mean) * rstd * gg[3] + bb[3]);
      *(u32x2*)(&yn[tt][l15 * 12 + i * 4]) = w;
    }
  }
  __syncthreads();  // B5: yn ready

  // ---- MLP: 16x192 -> 768 (gelu) -> 192, 4 hidden chunks of 192 ----
  bf16x8 ar[6];
#pragma unroll
  for (int ks = 0; ks < 6; ++ks)
    ar[ks] = *(const bf16x8*)(&yn[l15][ks * 32 + quad * 8]);

  f32x4 acc2[3];
#pragma unroll
  for (int nl = 0; nl < 3; ++nl) acc2[nl] = (f32x4){0.f, 0.f, 0.f, 0.f};

  for (int c = 0; c < 4; ++c) {
#pragma unroll
    for (int nl = 0; nl < 3; ++nl) {
      int gnt = c * 12 + wave * 3 + nl;
      const unsigned short* bp = w1p + ((size_t)(gnt * 6) * 64 + lane) * 8;
      f32x4 t0 = {0.f, 0.f, 0.f, 0.f};
#pragma unroll
      for (int ks = 0; ks < 6; ++ks) {
        bf16x8 bw = *(const bf16x8*)(bp + ks * 512);
        t0 = __builtin_amdgcn_mfma_f32_16x16x32_bf16(ar[ks], bw, t0, 0, 0, 0);
      }
      int lcol = wave * 48 + nl * 16 + l15;
      float bias = b1[c * 192 + lcol];
      unsigned int u0 = pk2(fast_gelu(t0[0] + bias), fast_gelu(t0[1] + bias));
      unsigned int u1 = pk2(fast_gelu(t0[2] + bias), fast_gelu(t0[3] + bias));
      hls[quad * 4 + 0][lcol] = (unsigned short)u0;
      hls[quad * 4 + 1][lcol] = (unsigned short)(u0 >> 16);
      hls[quad * 4 + 2][lcol] = (unsigned short)u1;
      hls[quad * 4 + 3][lcol] = (unsigned short)(u1 >> 16);
    }
    __syncthreads();  // hls chunk ready
    bf16x8 hr[6];
#pragma unroll
    for (int ks = 0; ks < 6; ++ks)
      hr[ks] = *(const bf16x8*)(&hls[l15][ks * 32 + quad * 8]);
#pragma unroll
    for (int nl = 0; nl < 3; ++nl) {
      int nt2 = wave * 3 + nl;
      const unsigned short* bp =
          w2p + ((size_t)(nt2 * 24 + c * 6) * 64 + lane) * 8;
#pragma unroll
      for (int ks = 0; ks < 6; ++ks) {
        bf16x8 bw = *(const bf16x8*)(bp + ks * 512);
        acc2[nl] =
            __builtin_amdgcn_mfma_f32_16x16x32_bf16(hr[ks], bw, acc2[nl], 0, 0, 0);
      }
    }
    __syncthreads();  // hls readers done -> next chunk may overwrite
  }

  // ---- epilogue: out = y + mlp + b2, pure store ----
#pragma unroll
  for (int nl = 0; nl < 3; ++nl) {
    int col = (wave * 3 + nl) * 16 + l15;
    float bias = b2[col];
#pragma unroll
    for (int r = 0; r < 4; ++r) {
      int p = quad * 4 + r;
      int hp = nh * 4 + (p >> 2), wp2 = nw * 4 + (p & 3);
      size_t oi = ((size_t)((b * 128 + hp) * 128 + wp2)) * 192 + col;
      out[oi] = sc[p][col] + acc2[nl][r] + bias;
    }
  }
}

extern "C" void kernel_launch(void* const* d_in, const int* in_sizes, int n_in,
                              void* d_out, int out_size, void* d_ws,
                              size_t ws_size, hipStream_t stream) {
  const float* x = (const float*)d_in[0];
  const float* n1g = (const float*)d_in[1];
  const float* n1b = (const float*)d_in[2];
  const float* pw = (const float*)d_in[3];
  const float* pb = (const float*)d_in[4];
  const float* qw = (const float*)d_in[5];
  const float* qb = (const float*)d_in[6];
  const float* aw = (const float*)d_in[7];
  const float* ab = (const float*)d_in[8];
  const float* n2g = (const float*)d_in[9];
  const float* n2b = (const float*)d_in[10];
  const float* w1 = (const float*)d_in[11];
  const float* b1 = (const float*)d_in[12];
  const float* w2 = (const float*)d_in[13];
  const float* b2 = (const float*)d_in[14];
  float* out = (float*)d_out;

  char* wsb = (char*)d_ws;
  unsigned short* qwp = (unsigned short*)wsb;               //    110,592 B
  unsigned short* awp = (unsigned short*)(wsb + 110592);    //     73,728 B
  unsigned short* w1p = (unsigned short*)(wsb + 184320);    //    294,912 B
  unsigned short* w2p = (unsigned short*)(wsb + 479232);    //    294,912 B
  unsigned short* pwp = (unsigned short*)(wsb + 774144);    //     36,864 B

  hipLaunchKernelGGL(k0_pack, dim3(198), dim3(256), 0, stream, qw, aw, w1, w2,
                     pw, qwp, awp, w1p, w2p, pwp);
  hipLaunchKernelGGL(k1234_fused, dim3(4096), dim3(256), 0, stream, x, n1g,
                     n1b, pwp, pb, qwp, qb, awp, ab, n2g, n2b, w1p, b1, w2p,
                     b2, out);
}